// Round 11
// baseline (60.454 us; speedup 1.0000x reference)
//
#include <hip/hip_runtime.h>

// LIF neuron forward scan: x [B,N,T] f32, T=256 contiguous (last axis).
// u = u*TAU + x_t; s = (u >= VTH); u = s ? 0 : u; emit s.
// TAU=0.125 (2^-3) -> u*TAU exact -> recurrence bit-matches numpy ref.
//
// R11: 4-way TIME-SPLIT for occupancy. R7-R10 all plateau at 45+-1us with
// ideal traffic -> either write-path ceiling (~3.15 TB/s -> floor 42.7us)
// or concurrency shortage (grid was capped at 8 waves/CU). This kernel
// discriminates: thread = (seq, quarter), 8192 waves = 32 waves/CU.
//  - Each quarter re-warms state over 16 steps from u=0: error at first
//    emitted step <= 8*2^-48 ~ 3e-14 (TAU=2^-3 decay); expected spike flips
//    over 33.5M steps ~1e-5, deterministic data -> validated = stable.
//  - Scan runs entirely in registers (scattered f32x4 loads, R5-proven
//    fetch-efficient); LDS holds only spikes (17.4KB/block, 2-way banks);
//    cooperative full-line stores (R8-proven exact 128MiB writes).

typedef float f32x4 __attribute__((ext_vector_type(4)));

constexpr int   T    = 256;
constexpr int   TV   = T / 4;      // 64 f32x4 per row
constexpr int   NQ   = 4;          // time-quarters per sequence
constexpr int   QV   = TV / NQ;    // 16 f32x4 per quarter
constexpr int   PH   = 4;          // phases per quarter
constexpr int   PV   = QV / PH;    // 4 f32x4 per phase (16 steps)
constexpr int   WV   = 4;          // warmup f32x4 (16 steps)
constexpr int   RP   = PV * 4 + 1; // 17 floats per LDS row-band (pad -> 2-way)
constexpr int   ROWS = 64;         // sequences per block
constexpr int   BAND = ROWS * RP;  // 1088 floats per quarter-band
constexpr float TAU  = 0.125f;
constexpr float VTH  = 1.0f;

__global__ __launch_bounds__(256, 4)
void lif_fwd(const f32x4* __restrict__ x, f32x4* __restrict__ out, int nseq) {
    __shared__ float lds[NQ * BAND];        // 17408 B -> 8 blocks/CU fits LDS

    const int tid  = threadIdx.x;
    const int q    = tid >> 6;              // wave-uniform quarter 0..3
    const int s    = tid & 63;              // sequence within block
    const int bseq = blockIdx.x * ROWS;
    const f32x4* xq = x + (size_t)(bseq + s) * TV + q * QV;

    float u = 0.0f;

    // ---- warmup (q>0): 16 steps ending at quarter start; no spikes emitted ----
    if (q > 0) {
        f32x4 w[WV];
        #pragma unroll
        for (int j = 0; j < WV; ++j) w[j] = xq[j - WV];
        #pragma unroll
        for (int j = 0; j < WV; ++j) {
            #pragma unroll
            for (int e = 0; e < 4; ++e) {
                u = u * TAU + w[j][e];
                u = (u >= VTH) ? 0.0f : u;
            }
        }
    }

    f32x4 cur[PV], nxt[PV];
    #pragma unroll
    for (int j = 0; j < PV; ++j) cur[j] = xq[j];

    float* myband = &lds[q * BAND + s * RP];
    const int r = tid >> 2, k = tid & 3;    // coop-store role

    #pragma unroll
    for (int p = 0; p < PH; ++p) {
        // prefetch next phase's input (1-deep; TLP from 32 waves/CU covers rest)
        if (p + 1 < PH) {
            #pragma unroll
            for (int j = 0; j < PV; ++j) nxt[j] = xq[(p + 1) * PV + j];
        }
        // scan 16 steps from registers; spikes -> own LDS row-band
        #pragma unroll
        for (int j = 0; j < PV; ++j) {
            #pragma unroll
            for (int e = 0; e < 4; ++e) {
                u = u * TAU + cur[j][e];
                bool b = (u >= VTH);
                myband[j * 4 + e] = b ? 1.0f : 0.0f;   // banks (17s+c)%32: 2-way
                u = b ? 0.0f : u;
            }
        }
        __syncthreads();
        // cooperative store: round m covers band m; 16 consecutive steps of a
        // row = 64B full line; 64 segments per round, all fully covered.
        #pragma unroll
        for (int m = 0; m < NQ; ++m) {
            const float* pp = &lds[m * BAND + r * RP + k * 4];
            f32x4 v; v.x = pp[0]; v.y = pp[1]; v.z = pp[2]; v.w = pp[3];
            out[(size_t)(bseq + r) * TV + m * QV + p * PV + k] = v;
        }
        __syncthreads();                    // LDS safe to overwrite next phase
        if (p + 1 < PH) {
            #pragma unroll
            for (int j = 0; j < PV; ++j) cur[j] = nxt[j];
        }
    }
}

extern "C" void kernel_launch(void* const* d_in, const int* in_sizes, int n_in,
                              void* d_out, int out_size, void* d_ws, size_t ws_size,
                              hipStream_t stream) {
    const float* x = (const float*)d_in[0];
    float* out = (float*)d_out;

    int nseq = in_sizes[0] / T;             // 131072 sequences
    int grid = nseq / ROWS;                 // 2048 blocks of 256 threads

    lif_fwd<<<grid, 256, 0, stream>>>(
        (const f32x4*)x, (f32x4*)out, nseq);
}